// Round 1
// baseline (451.706 us; speedup 1.0000x reference)
//
#include <hip/hip_runtime.h>

typedef unsigned int u32;
typedef unsigned short u16;
typedef __attribute__((ext_vector_type(8))) short short8;   // 8 x bf16 (guide-verified frag type)
typedef __attribute__((ext_vector_type(4))) float f32x4;

__device__ __forceinline__ u16 f2bf(float f) {
    u32 u = __float_as_uint(f);
    u32 r = (u + 0x7fffu + ((u >> 16) & 1u)) >> 16;   // RNE
    return (u16)r;
}
__device__ __forceinline__ float bf2f(u32 lo16) { return __uint_as_float(lo16 << 16); }

// packed accumulate: a[i] += {lo(w), hi(w)} ; hi is free via mask (bf16 hi-half IS f32),
// lo via one shift. Pairs encourage v_pk_add_f32.
__device__ __forceinline__ void acc_u4p(float2* a, uint4 v) {
    u32 w[4] = {v.x, v.y, v.z, v.w};
#pragma unroll
    for (int i = 0; i < 4; i++) {
        float2 t;
        t.x = __uint_as_float(w[i] << 16);
        t.y = __uint_as_float(w[i] & 0xffff0000u);
        a[i].x += t.x;
        a[i].y += t.y;
    }
}

// ---------------- prep ----------------

// fused transposed weights for all 3 layers in one launch
__global__ __launch_bounds__(256) void prep_w_all(const float* __restrict__ ws0, const float* __restrict__ wn0, u16* __restrict__ wt0,
                                                  const float* __restrict__ ws1, const float* __restrict__ wn1, u16* __restrict__ wt1,
                                                  const float* __restrict__ ws2, const float* __restrict__ wn2, u16* __restrict__ wt2) {
    int bid = blockIdx.x;
    const float *ws, *wn;
    u16* wt;
    int dout, HW, local;
    if (bid < 128)      { ws = ws0; wn = wn0; wt = wt0; dout = 128; HW = 128; local = bid; }
    else if (bid < 256) { ws = ws1; wn = wn1; wt = wt1; dout = 128; HW = 128; local = bid - 128; }
    else                { ws = ws2; wn = wn2; wt = wt2; dout = 47;  HW = 64;  local = bid - 256; }
    int idx = local * 256 + threadIdx.x;   // idx = n*128 + k
    int n = idx >> 7, k = idx & 127;
    float v = 0.f;
    if (n < HW) { if (n < dout) v = ws[k * dout + n]; }
    else { int nn = n - HW; if (nn < dout) v = wn[k * dout + nn]; }
    wt[idx] = f2bf(v);
}

// ---------------- CSR build ----------------

__global__ __launch_bounds__(256) void hist_k(const int* __restrict__ dst,
                                              int* __restrict__ deg, int E) {
    int i = blockIdx.x * 256 + threadIdx.x;
    if (i < E) atomicAdd(&deg[dst[i]], 1);
}

__global__ __launch_bounds__(256) void scan_partial(const int* __restrict__ deg,
                                                    int* __restrict__ bsum, int Nn) {
    __shared__ int sm[256];
    int t = threadIdx.x;
    int base = blockIdx.x * 1024 + t * 4;
    int s = 0;
#pragma unroll
    for (int j = 0; j < 4; j++)
        if (base + j < Nn) s += deg[base + j];
    sm[t] = s;
    __syncthreads();
    for (int off = 128; off > 0; off >>= 1) {
        if (t < off) sm[t] += sm[t + off];
        __syncthreads();
    }
    if (t == 0) bsum[blockIdx.x] = sm[0];
}

__global__ __launch_bounds__(256) void scan_offsets(const int* __restrict__ bsum,
                                                    int* __restrict__ boff, int nb) {
    __shared__ int sm[256];
    int t = threadIdx.x;
    int v = (t < nb) ? bsum[t] : 0;
    sm[t] = v;
    __syncthreads();
    for (int off = 1; off < 256; off <<= 1) {
        int u = (t >= off) ? sm[t - off] : 0;
        __syncthreads();
        sm[t] += u;
        __syncthreads();
    }
    if (t < nb) boff[t] = sm[t] - v;
}

// rowptr + invd + bucket cursor init (cursor[b] = rowptr[b*512])
__global__ __launch_bounds__(1024) void scan_final(const int* __restrict__ deg,
                                                   const int* __restrict__ boff,
                                                   int* __restrict__ rowptr,
                                                   float* __restrict__ invd,
                                                   int* __restrict__ cursor,
                                                   int Nn, int E) {
    __shared__ int sm[1024];
    int t = threadIdx.x;
    int i = blockIdx.x * 1024 + t;
    int v = (i < Nn) ? deg[i] : 0;
    sm[t] = v;
    __syncthreads();
    for (int off = 1; off < 1024; off <<= 1) {
        int u = (t >= off) ? sm[t - off] : 0;
        __syncthreads();
        sm[t] += u;
        __syncthreads();
    }
    if (i < Nn) {
        int rp = boff[blockIdx.x] + sm[t] - v;   // exclusive
        rowptr[i] = rp;
        invd[i] = 1.0f / (float)max(v, 1);
        if ((i & 511) == 0) cursor[i >> 9] = rp;
    }
    if (i == Nn) rowptr[Nn] = E;
}

// multisplit pass 1: tile -> LDS bucket-compaction -> contiguous bucket segments
#define TILE 4096
__global__ __launch_bounds__(512) void bucket_scatter(const int* __restrict__ src,
                                                      const int* __restrict__ dst,
                                                      int* __restrict__ cursor,
                                                      uint2* __restrict__ pairs, int E) {
    __shared__ uint2 sp[TILE];                         // 32 KB
    __shared__ int s_cnt[256], s_off[256], s_gpos[256], s_cnt2[256];
    const int tid = threadIdx.x;
    const int base = blockIdx.x * TILE;
    const int tn = min(TILE, E - base);
    if (tid < 256) { s_cnt[tid] = 0; s_cnt2[tid] = 0; }
    __syncthreads();
    int d[8], s[8];
#pragma unroll
    for (int j = 0; j < 8; j++) {
        int k = tid + j * 512;
        if (k < tn) {
            d[j] = dst[base + k];
            s[j] = src[base + k];
            atomicAdd(&s_cnt[d[j] >> 9], 1);
        } else d[j] = -1;
    }
    __syncthreads();
    if (tid < 256) s_off[tid] = s_cnt[tid];
    __syncthreads();
    for (int off = 1; off < 256; off <<= 1) {
        int v = 0;
        if (tid < 256 && tid >= off) v = s_off[tid - off];
        __syncthreads();
        if (tid < 256) s_off[tid] += v;
        __syncthreads();
    }
    if (tid < 256 && s_cnt[tid] > 0) s_gpos[tid] = atomicAdd(&cursor[tid], s_cnt[tid]);
    __syncthreads();
#pragma unroll
    for (int j = 0; j < 8; j++) {
        if (d[j] >= 0) {
            int b = d[j] >> 9;
            int p = atomicAdd(&s_cnt2[b], 1);
            sp[s_off[b] - s_cnt[b] + p] = make_uint2((u32)d[j], (u32)s[j]);
        }
    }
    __syncthreads();
    for (int k = tid; k < tn; k += 512) {
        uint2 pr = sp[k];
        int b = (int)(pr.x >> 9);
        pairs[s_gpos[b] + (k - (s_off[b] - s_cnt[b]))] = pr;
    }
}

// multisplit pass 2: per-bucket exact CSR placement via LDS counters, coalesced writeback
#define LDSCAP 12288
__global__ __launch_bounds__(512) void build_csr(const uint2* __restrict__ pairs,
                                                 const int* __restrict__ rowptr,
                                                 int* __restrict__ cols, int Nn) {
    __shared__ int s_cols[LDSCAP];                     // 48 KB
    __shared__ int s_row[513];
    __shared__ int s_cnt[512];
    const int tid = threadIdx.x;
    const int d0 = blockIdx.x * 512;
    const int nd = min(512, Nn - d0);
    for (int i = tid; i <= nd; i += 512) s_row[i] = rowptr[d0 + i];
    if (tid < nd) s_cnt[tid] = 0;
    __syncthreads();
    const int base = s_row[0];
    const int n = s_row[nd] - base;
    const bool fit = (n <= LDSCAP);
    for (int k = tid; k < n; k += 512) {
        uint2 pr = pairs[base + k];
        int dl = (int)pr.x - d0;
        int p = atomicAdd(&s_cnt[dl], 1);
        int pos = s_row[dl] - base + p;
        if (fit) s_cols[pos] = (int)pr.y;
        else cols[base + pos] = (int)pr.y;             // overflow fallback (never expected)
    }
    __syncthreads();
    if (fit)
        for (int k = tid; k < n; k += 512) cols[base + k] = s_cols[k];
}

// ---------------- fused GEMM: C[M][NCOLS] = A[M][128] @ Bt^T  (fp32 acc) ----------------
// AF32: A is fp32 (layer 0 reads x directly, converts during LDS staging).
// Epilogue: acc -> LDS (As reused) -> coalesced uint4 stores (16 B/lane).
#define KDIM 128
#define KP 136

template <int NCOLS, bool AF32>
__global__ __launch_bounds__(256) void gemm_bf16(const void* __restrict__ Ap,
                                                 const u16* __restrict__ Bt,
                                                 u16* __restrict__ C, int M) {
    __shared__ u16 As[64 * KP];
    __shared__ u16 Bs[128 * KP];
    const int row0 = blockIdx.x * 64;
    const int col0 = blockIdx.y * 128;
    const int tid = threadIdx.x;

#pragma unroll
    for (int i = 0; i < 4; i++) {
        int idx = tid + i * 256;
        int r = idx >> 4, c = idx & 15;
        uint4 v = make_uint4(0, 0, 0, 0);
        if (row0 + r < M) {
            if (AF32) {
                const float* Af = (const float*)Ap;
                const float4* rowp = (const float4*)(Af + (size_t)(row0 + r) * KDIM);
                float4 f0 = rowp[2 * c];
                float4 f1 = rowp[2 * c + 1];
                v.x = (u32)f2bf(f0.x) | ((u32)f2bf(f0.y) << 16);
                v.y = (u32)f2bf(f0.z) | ((u32)f2bf(f0.w) << 16);
                v.z = (u32)f2bf(f1.x) | ((u32)f2bf(f1.y) << 16);
                v.w = (u32)f2bf(f1.z) | ((u32)f2bf(f1.w) << 16);
            } else {
                const u16* Ab = (const u16*)Ap;
                v = ((const uint4*)(Ab + (size_t)(row0 + r) * KDIM))[c];
            }
        }
        ((uint4*)(As + r * KP))[c] = v;
    }
#pragma unroll
    for (int i = 0; i < 8; i++) {
        int idx = tid + i * 256;
        int r = idx >> 4, c = idx & 15;
        uint4 v = ((const uint4*)(Bt + (size_t)(col0 + r) * KDIM))[c];
        ((uint4*)(Bs + r * KP))[c] = v;
    }
    __syncthreads();

    const int lane = tid & 63, wave = tid >> 6;
    const int quad = lane >> 4, l16 = lane & 15;
    const int wcol = wave * 32;

    f32x4 acc[4][2];
#pragma unroll
    for (int mt = 0; mt < 4; mt++)
#pragma unroll
        for (int nt = 0; nt < 2; nt++) acc[mt][nt] = (f32x4){0.f, 0.f, 0.f, 0.f};

#pragma unroll
    for (int kc = 0; kc < 4; kc++) {
        short8 a[4], b[2];
#pragma unroll
        for (int mt = 0; mt < 4; mt++)
            a[mt] = *(const short8*)(As + (size_t)(mt * 16 + l16) * KP + kc * 32 + quad * 8);
#pragma unroll
        for (int nt = 0; nt < 2; nt++)
            b[nt] = *(const short8*)(Bs + (size_t)(wcol + nt * 16 + l16) * KP + kc * 32 + quad * 8);
#pragma unroll
        for (int mt = 0; mt < 4; mt++)
#pragma unroll
            for (int nt = 0; nt < 2; nt++)
                acc[mt][nt] = __builtin_amdgcn_mfma_f32_16x16x32_bf16(a[mt], b[nt], acc[mt][nt], 0, 0, 0);
    }

    // Epilogue: C/D layout col=lane&15, row=quad*4+reg [verified m89/m91].
    // Scalar 2B stores scatter badly -> round-trip through As (dead after MFMAs)
    // and store coalesced 16 B/lane.
    __syncthreads();                                    // all waves done reading As/Bs
#pragma unroll
    for (int mt = 0; mt < 4; mt++)
#pragma unroll
        for (int i = 0; i < 4; i++) {
            int rl = mt * 16 + quad * 4 + i;
#pragma unroll
            for (int nt = 0; nt < 2; nt++)
                As[rl * KP + wcol + nt * 16 + l16] = f2bf(acc[mt][nt][i]);
        }
    __syncthreads();
#pragma unroll
    for (int it = 0; it < 4; it++) {
        int idx = tid + it * 256;
        int r = idx >> 4, c8 = idx & 15;                // 16 x uint4 per 128-col row
        if (row0 + r < M)
            *(uint4*)(C + (size_t)(row0 + r) * NCOLS + col0 + c8 * 8) =
                *(const uint4*)(As + r * KP + c8 * 8);
    }
}

// ---------------- 128-col aggregation: 1 node/wave, 4 slots x 16 lanes, 4 gathers in flight ----------------
// out2 = [M+1][256] bf16 (s | t); row M is a zero row (OOB pad target).
// Slot `sub` covers edges beg+sub+4k in the SAME order as before (bitwise-identical sums).
template <bool RELU>
__global__ __launch_bounds__(256) void agg128_k(const u16* __restrict__ out2,
                                                const int* __restrict__ rowptr,
                                                const int* __restrict__ cols,
                                                const float* __restrict__ invd,
                                                const float* __restrict__ bias,
                                                u16* __restrict__ outp, int Mn) {
    int wave = threadIdx.x >> 6, lane = threadIdx.x & 63;
    int node = blockIdx.x * 4 + wave;
    if (node >= Mn) return;
    int sub = lane >> 4, l16 = lane & 15;               // 4 slots x 16 lanes
    const u16* tb = out2 + 128 + 8 * l16;
    int beg = rowptr[node], end = rowptr[node + 1];
    float2 a[4];
#pragma unroll
    for (int i = 0; i < 4; i++) a[i] = make_float2(0.f, 0.f);
    int e = beg + sub;
    while (e < end) {
        // cols is padded by 32 ints, so speculative loads are in-bounds;
        // OOB slots redirect to the zero row (index Mn) -> no register zeroing.
        int s0 = cols[e];                               // e < end guaranteed by loop cond
        int s1 = (e + 4  < end) ? cols[e + 4]  : Mn;
        int s2 = (e + 8  < end) ? cols[e + 8]  : Mn;
        int s3 = (e + 12 < end) ? cols[e + 12] : Mn;
        uint4 v0 = *(const uint4*)(tb + (size_t)s0 * 256);
        uint4 v1 = *(const uint4*)(tb + (size_t)s1 * 256);
        uint4 v2 = *(const uint4*)(tb + (size_t)s2 * 256);
        uint4 v3 = *(const uint4*)(tb + (size_t)s3 * 256);
        acc_u4p(a, v0); acc_u4p(a, v1); acc_u4p(a, v2); acc_u4p(a, v3);
        e += 16;
    }
    float af[8] = {a[0].x, a[0].y, a[1].x, a[1].y, a[2].x, a[2].y, a[3].x, a[3].y};
#pragma unroll
    for (int j = 0; j < 8; j++) {                       // reduce across 4 slots
        af[j] += __shfl_xor(af[j], 16); af[j] += __shfl_xor(af[j], 32);
    }
    if (sub == 0) {
        float id = invd[node];
        uint4 sv = *(const uint4*)(out2 + (size_t)node * 256 + 8 * l16);
        float4 b0 = *(const float4*)(bias + 8 * l16);
        float4 b1 = *(const float4*)(bias + 8 * l16 + 4);
        float o0 = bf2f(sv.x & 0xffffu) + af[0] * id + b0.x;
        float o1 = bf2f(sv.x >> 16)     + af[1] * id + b0.y;
        float o2 = bf2f(sv.y & 0xffffu) + af[2] * id + b0.z;
        float o3 = bf2f(sv.y >> 16)     + af[3] * id + b0.w;
        float o4 = bf2f(sv.z & 0xffffu) + af[4] * id + b1.x;
        float o5 = bf2f(sv.z >> 16)     + af[5] * id + b1.y;
        float o6 = bf2f(sv.w & 0xffffu) + af[6] * id + b1.z;
        float o7 = bf2f(sv.w >> 16)     + af[7] * id + b1.w;
        if (RELU) {
            o0 = fmaxf(o0, 0.f); o1 = fmaxf(o1, 0.f); o2 = fmaxf(o2, 0.f); o3 = fmaxf(o3, 0.f);
            o4 = fmaxf(o4, 0.f); o5 = fmaxf(o5, 0.f); o6 = fmaxf(o6, 0.f); o7 = fmaxf(o7, 0.f);
        }
        uint4 w;
        w.x = (u32)f2bf(o0) | ((u32)f2bf(o1) << 16);
        w.y = (u32)f2bf(o2) | ((u32)f2bf(o3) << 16);
        w.z = (u32)f2bf(o4) | ((u32)f2bf(o5) << 16);
        w.w = (u32)f2bf(o6) | ((u32)f2bf(o7) << 16);
        *(uint4*)(outp + (size_t)node * 128 + 8 * l16) = w;
    }
}

// ---------------- layer-2 aggregation: 1 node/wave, 8 slots x 8 lanes, 4 gathers in flight ----------------
// out2 = [M+1][128] bf16: s at cols 0..63 (live 0..46), t at cols 64..127 (live 64..110).
// Row M is a zero row (memset just before this kernel).
__global__ __launch_bounds__(256) void agg_out8_k(const u16* __restrict__ out2,
                                                  const int* __restrict__ rowptr,
                                                  const int* __restrict__ cols,
                                                  const float* __restrict__ invd,
                                                  const float* __restrict__ bias,
                                                  float* __restrict__ outp, int Mn) {
    int wave = threadIdx.x >> 6, lane = threadIdx.x & 63;
    int node = blockIdx.x * 4 + wave;
    if (node >= Mn) return;
    int e8 = lane >> 3, l8 = lane & 7;                  // 8 slots x 8 lanes
    const u16* tb = out2 + 64 + 8 * l8;
    int beg = rowptr[node], end = rowptr[node + 1];
    float2 a[4];
#pragma unroll
    for (int i = 0; i < 4; i++) a[i] = make_float2(0.f, 0.f);
    int e = beg + e8;
    while (e < end) {
        int s0 = cols[e];
        int s1 = (e + 8  < end) ? cols[e + 8]  : Mn;
        int s2 = (e + 16 < end) ? cols[e + 16] : Mn;
        int s3 = (e + 24 < end) ? cols[e + 24] : Mn;
        uint4 v0 = *(const uint4*)(tb + (size_t)s0 * 128);
        uint4 v1 = *(const uint4*)(tb + (size_t)s1 * 128);
        uint4 v2 = *(const uint4*)(tb + (size_t)s2 * 128);
        uint4 v3 = *(const uint4*)(tb + (size_t)s3 * 128);
        acc_u4p(a, v0); acc_u4p(a, v1); acc_u4p(a, v2); acc_u4p(a, v3);
        e += 32;
    }
    float af[8] = {a[0].x, a[0].y, a[1].x, a[1].y, a[2].x, a[2].y, a[3].x, a[3].y};
#pragma unroll
    for (int j = 0; j < 8; j++) {                       // reduce across 8 slots
        af[j] += __shfl_xor(af[j], 8); af[j] += __shfl_xor(af[j], 16); af[j] += __shfl_xor(af[j], 32);
    }
    if (e8 == 0) {
        float id = invd[node];
        uint4 sv = *(const uint4*)(out2 + (size_t)node * 128 + 8 * l8);
        u32 sw[4] = {sv.x, sv.y, sv.z, sv.w};
        float* orow = outp + (size_t)node * 47;
#pragma unroll
        for (int j = 0; j < 8; j++) {
            int c = 8 * l8 + j;
            if (c < 47) {
                float s = bf2f((j & 1) ? (sw[j >> 1] >> 16) : (sw[j >> 1] & 0xffffu));
                orow[c] = s + af[j] * id + bias[c];
            }
        }
    }
}

// ---------------- launch ----------------

extern "C" void kernel_launch(void* const* d_in, const int* in_sizes, int n_in,
                              void* d_out, int out_size, void* d_ws, size_t ws_size,
                              hipStream_t stream) {
    const float* x   = (const float*)d_in[0];
    const int*   src = (const int*)d_in[1];
    const int*   dst = (const int*)d_in[2];
    const float* ws0 = (const float*)d_in[3];
    const float* wn0 = (const float*)d_in[4];
    const float* b0  = (const float*)d_in[5];
    const float* ws1 = (const float*)d_in[6];
    const float* wn1 = (const float*)d_in[7];
    const float* b1  = (const float*)d_in[8];
    const float* ws2 = (const float*)d_in[9];
    const float* wn2 = (const float*)d_in[10];
    const float* b2  = (const float*)d_in[11];

    const int Nn = in_sizes[0] / 128;   // 100000
    const int E  = in_sizes[1];         // 1600000

    char* p = (char*)d_ws;
    auto alloc = [&](size_t bytes) -> void* {
        void* r = (void*)p;
        p += (bytes + 255) & ~(size_t)255;
        return r;
    };
    u16*   bufA   = (u16*)alloc((size_t)Nn * 128 * 2);            // h1 / h2
    u16*   out2   = (u16*)alloc(((size_t)Nn * 256 + 256) * 2);    // [s|t] per layer + 1 zero pad row; ALSO overlaid as pairs buf
    u16*   wt0    = (u16*)alloc(256 * 128 * 2);
    u16*   wt1    = (u16*)alloc(256 * 128 * 2);
    u16*   wt2    = (u16*)alloc(128 * 128 * 2);
    int*   deg    = (int*)alloc((size_t)Nn * 4);
    int*   rowptr = (int*)alloc((size_t)(Nn + 1) * 4);
    float* invd   = (float*)alloc((size_t)Nn * 4);
    int*   cols   = (int*)alloc((size_t)(E + 32) * 4);            // +32 pad: speculative in-flight loads
    int*   bsum   = (int*)alloc(256 * 4);
    int*   boff   = (int*)alloc(256 * 4);
    int*   cursor = (int*)alloc(256 * 4);
    uint2* pairs  = (uint2*)out2;                                 // overlay: out2 unused until gemm layer 0

    hipMemsetAsync(deg, 0, (size_t)Nn * 4, stream);
    // zero pad row for the 256-col layout (row Nn, byte offset Nn*512; beyond pairs overlay)
    hipMemsetAsync(out2 + (size_t)Nn * 256, 0, 512, stream);

    prep_w_all<<<320, 256, 0, stream>>>(ws0, wn0, wt0, ws1, wn1, wt1, ws2, wn2, wt2);

    hist_k<<<(E + 255) / 256, 256, 0, stream>>>(dst, deg, E);
    const int nb = (Nn + 1023) / 1024;
    const int nb2 = (Nn + 1 + 1023) / 1024;
    scan_partial<<<nb, 256, 0, stream>>>(deg, bsum, Nn);
    scan_offsets<<<1, 256, 0, stream>>>(bsum, boff, nb);
    scan_final<<<nb2, 1024, 0, stream>>>(deg, boff, rowptr, invd, cursor, Nn, E);

    bucket_scatter<<<(E + TILE - 1) / TILE, 512, 0, stream>>>(src, dst, cursor, pairs, E);
    build_csr<<<(Nn + 511) / 512, 512, 0, stream>>>(pairs, rowptr, cols, Nn);

    dim3 ggrid((Nn + 63) / 64, 2);
    dim3 ggrid1((Nn + 63) / 64, 1);
    const int aggGrid = (Nn + 3) / 4;                    // 4 waves x 1 node = 4 nodes/block
    // layer 0: LDS-staged GEMM reads x fp32 directly (cvt fused into staging)
    gemm_bf16<256, true><<<ggrid, 256, 0, stream>>>(x, wt0, out2, Nn);
    agg128_k<true><<<aggGrid, 256, 0, stream>>>(out2, rowptr, cols, invd, b0, bufA, Nn);
    // layer 1
    gemm_bf16<256, false><<<ggrid, 256, 0, stream>>>(bufA, wt1, out2, Nn);
    agg128_k<true><<<aggGrid, 256, 0, stream>>>(out2, rowptr, cols, invd, b1, bufA, Nn);
    // layer 2: N=128 (48 self + 48 neigh, padded)
    gemm_bf16<128, false><<<ggrid1, 256, 0, stream>>>(bufA, wt2, out2, Nn);
    // zero pad row for the 128-col layout (row Nn, byte offset Nn*256); must be after
    // layer-1 consumers of that region (stream-ordered here, after gemm<128>)
    hipMemsetAsync(out2 + (size_t)Nn * 128, 0, 256, stream);
    agg_out8_k<<<aggGrid, 256, 0, stream>>>(out2, rowptr, cols, invd, b2, (float*)d_out, Nn);
}

// Round 3
// 393.804 us; speedup vs baseline: 1.1470x; 1.1470x over previous
//
#include <hip/hip_runtime.h>

typedef unsigned int u32;
typedef unsigned short u16;
typedef __attribute__((ext_vector_type(8))) short short8;   // 8 x bf16 (guide-verified frag type)
typedef __attribute__((ext_vector_type(4))) float f32x4;

__device__ __forceinline__ u16 f2bf(float f) {
    u32 u = __float_as_uint(f);
    u32 r = (u + 0x7fffu + ((u >> 16) & 1u)) >> 16;   // RNE
    return (u16)r;
}
__device__ __forceinline__ float bf2f(u32 lo16) { return __uint_as_float(lo16 << 16); }

// packed accumulate: a[i] += {lo(w), hi(w)} ; hi is free via mask (bf16 hi-half IS f32),
// lo via one shift. Pairs encourage v_pk_add_f32.
__device__ __forceinline__ void acc_u4p(float2* a, uint4 v) {
    u32 w[4] = {v.x, v.y, v.z, v.w};
#pragma unroll
    for (int i = 0; i < 4; i++) {
        float2 t;
        t.x = __uint_as_float(w[i] << 16);
        t.y = __uint_as_float(w[i] & 0xffff0000u);
        a[i].x += t.x;
        a[i].y += t.y;
    }
}

// ---------------- prep ----------------

// fused transposed weights for all 3 layers in one launch
__global__ __launch_bounds__(256) void prep_w_all(const float* __restrict__ ws0, const float* __restrict__ wn0, u16* __restrict__ wt0,
                                                  const float* __restrict__ ws1, const float* __restrict__ wn1, u16* __restrict__ wt1,
                                                  const float* __restrict__ ws2, const float* __restrict__ wn2, u16* __restrict__ wt2) {
    int bid = blockIdx.x;
    const float *ws, *wn;
    u16* wt;
    int dout, HW, local;
    if (bid < 128)      { ws = ws0; wn = wn0; wt = wt0; dout = 128; HW = 128; local = bid; }
    else if (bid < 256) { ws = ws1; wn = wn1; wt = wt1; dout = 128; HW = 128; local = bid - 128; }
    else                { ws = ws2; wn = wn2; wt = wt2; dout = 47;  HW = 64;  local = bid - 256; }
    int idx = local * 256 + threadIdx.x;   // idx = n*128 + k
    int n = idx >> 7, k = idx & 127;
    float v = 0.f;
    if (n < HW) { if (n < dout) v = ws[k * dout + n]; }
    else { int nn = n - HW; if (nn < dout) v = wn[k * dout + nn]; }
    wt[idx] = f2bf(v);
}

// ---------------- CSR build ----------------
// No 100K-bin global-atomic histogram: only 256 BUCKET totals are needed up front
// (LDS-privatized -> ~256 global atomics per block instead of 2048 scattered ones).
// Per-node degrees/rowptr/invd are computed inside build_csr2 where each bucket's
// 512 nodes fit LDS counters.

__global__ __launch_bounds__(256) void hist256(const int* __restrict__ dst,
                                               int* __restrict__ bcnt, int E) {
    __shared__ int bins[256];
    bins[threadIdx.x] = 0;
    __syncthreads();
    int gid = blockIdx.x * 256 + threadIdx.x;
    int stride = gridDim.x * 256;
    const int4* d4 = (const int4*)dst;
    int n4 = E >> 2;
    for (int k = gid; k < n4; k += stride) {
        int4 v = d4[k];
        atomicAdd(&bins[v.x >> 9], 1);
        atomicAdd(&bins[v.y >> 9], 1);
        atomicAdd(&bins[v.z >> 9], 1);
        atomicAdd(&bins[v.w >> 9], 1);
    }
    for (int k = (n4 << 2) + gid; k < E; k += stride)
        atomicAdd(&bins[dst[k] >> 9], 1);
    __syncthreads();
    int b = bins[threadIdx.x];
    if (b) atomicAdd(&bcnt[threadIdx.x], b);
}

// exclusive scan of the 256 bucket counts -> boff (+ total at boff[256]) + cursor init
__global__ __launch_bounds__(256) void scan256(const int* __restrict__ bcnt,
                                               int* __restrict__ boff,
                                               int* __restrict__ cursor) {
    __shared__ int sm[256];
    int t = threadIdx.x;
    int v = bcnt[t];
    sm[t] = v;
    __syncthreads();
    for (int off = 1; off < 256; off <<= 1) {
        int u = (t >= off) ? sm[t - off] : 0;
        __syncthreads();
        sm[t] += u;
        __syncthreads();
    }
    int excl = sm[t] - v;
    boff[t] = excl;
    cursor[t] = excl;
    if (t == 255) boff[256] = sm[255];   // == E
}

// multisplit pass 1: tile -> LDS bucket-compaction -> contiguous bucket segments
#define TILE 4096
__global__ __launch_bounds__(512) void bucket_scatter(const int* __restrict__ src,
                                                      const int* __restrict__ dst,
                                                      int* __restrict__ cursor,
                                                      uint2* __restrict__ pairs, int E) {
    __shared__ uint2 sp[TILE];                         // 32 KB
    __shared__ int s_cnt[256], s_off[256], s_gpos[256], s_cnt2[256];
    const int tid = threadIdx.x;
    const int base = blockIdx.x * TILE;
    const int tn = min(TILE, E - base);
    if (tid < 256) { s_cnt[tid] = 0; s_cnt2[tid] = 0; }
    __syncthreads();
    int d[8], s[8];
#pragma unroll
    for (int j = 0; j < 8; j++) {
        int k = tid + j * 512;
        if (k < tn) {
            d[j] = dst[base + k];
            s[j] = src[base + k];
            atomicAdd(&s_cnt[d[j] >> 9], 1);
        } else d[j] = -1;
    }
    __syncthreads();
    if (tid < 256) s_off[tid] = s_cnt[tid];
    __syncthreads();
    for (int off = 1; off < 256; off <<= 1) {
        int v = 0;
        if (tid < 256 && tid >= off) v = s_off[tid - off];
        __syncthreads();
        if (tid < 256) s_off[tid] += v;
        __syncthreads();
    }
    if (tid < 256 && s_cnt[tid] > 0) s_gpos[tid] = atomicAdd(&cursor[tid], s_cnt[tid]);
    __syncthreads();
#pragma unroll
    for (int j = 0; j < 8; j++) {
        if (d[j] >= 0) {
            int b = d[j] >> 9;
            int p = atomicAdd(&s_cnt2[b], 1);
            sp[s_off[b] - s_cnt[b] + p] = make_uint2((u32)d[j], (u32)s[j]);
        }
    }
    __syncthreads();
    for (int k = tid; k < tn; k += 512) {
        uint2 pr = sp[k];
        int b = (int)(pr.x >> 9);
        pairs[s_gpos[b] + (k - (s_off[b] - s_cnt[b]))] = pr;
    }
}

// multisplit pass 2 (fused with degree/rowptr/invd):
//   pass A: read pairs ONCE, count per-node in LDS, stash packed (dl<<17|src) in LDS
//   scan 512 counts -> rowptr (bucket base + excl) + invd
//   pass B: place from LDS stash into s_cols, coalesced writeback
#define LDSCAP 12288
__global__ __launch_bounds__(512) void build_csr2(const uint2* __restrict__ pairs,
                                                  const int* __restrict__ boff,
                                                  int* __restrict__ rowptr,
                                                  float* __restrict__ invd,
                                                  int* __restrict__ cols, int Nn, int E) {
    __shared__ int s_pack[LDSCAP];                     // 48 KB: (dl<<17)|src stash
    __shared__ int s_cols[LDSCAP];                     // 48 KB: placed cols
    __shared__ int s_cnt[512];
    __shared__ int s_off[512];
    __shared__ int s_cnt2[512];
    const int tid = threadIdx.x;
    const int d0 = blockIdx.x * 512;
    const int nd = min(512, Nn - d0);
    const int base = boff[blockIdx.x];
    const int n = boff[blockIdx.x + 1] - base;
    const bool fit = (n <= LDSCAP);
    s_cnt[tid] = 0; s_cnt2[tid] = 0;
    __syncthreads();
    for (int k = tid; k < n; k += 512) {
        uint2 pr = pairs[base + k];
        int dl = (int)pr.x - d0;
        atomicAdd(&s_cnt[dl], 1);
        if (fit) s_pack[k] = (dl << 17) | (int)pr.y;   // src < 2^17 (N=100000)
    }
    __syncthreads();
    int v = s_cnt[tid];
    s_off[tid] = v;
    __syncthreads();
    for (int off = 1; off < 512; off <<= 1) {
        int u = (tid >= off) ? s_off[tid - off] : 0;
        __syncthreads();
        s_off[tid] += u;
        __syncthreads();
    }
    int excl = s_off[tid] - v;                         // exclusive prefix
    if (tid < nd) {
        rowptr[d0 + tid] = base + excl;
        invd[d0 + tid] = 1.0f / (float)max(v, 1);
    }
    if (blockIdx.x == 0 && tid == 0) rowptr[Nn] = E;
    s_off[tid] = excl;                                 // own-slot overwrite (no cross reads pending)
    __syncthreads();
    if (fit) {
        for (int k = tid; k < n; k += 512) {
            int pk = s_pack[k];
            int dl = pk >> 17;
            int p = atomicAdd(&s_cnt2[dl], 1);
            s_cols[s_off[dl] + p] = pk & 0x1ffff;
        }
        __syncthreads();
        for (int k = tid; k < n; k += 512) cols[base + k] = s_cols[k];
    } else {                                           // overflow fallback (never expected)
        for (int k = tid; k < n; k += 512) {
            uint2 pr = pairs[base + k];
            int dl = (int)pr.x - d0;
            int p = atomicAdd(&s_cnt2[dl], 1);
            cols[base + s_off[dl] + p] = (int)pr.y;
        }
    }
}

// ---------------- fused GEMM: C[M][NCOLS] = A[M][128] @ Bt^T  (fp32 acc) ----------------
// AF32: A is fp32 (layer 0 reads x directly, converts during LDS staging).
// Epilogue: acc -> LDS (As reused) -> coalesced uint4 stores (16 B/lane).
#define KDIM 128
#define KP 136

template <int NCOLS, bool AF32>
__global__ __launch_bounds__(256) void gemm_bf16(const void* __restrict__ Ap,
                                                 const u16* __restrict__ Bt,
                                                 u16* __restrict__ C, int M) {
    __shared__ u16 As[64 * KP];
    __shared__ u16 Bs[128 * KP];
    const int row0 = blockIdx.x * 64;
    const int col0 = blockIdx.y * 128;
    const int tid = threadIdx.x;

#pragma unroll
    for (int i = 0; i < 4; i++) {
        int idx = tid + i * 256;
        int r = idx >> 4, c = idx & 15;
        uint4 v = make_uint4(0, 0, 0, 0);
        if (row0 + r < M) {
            if (AF32) {
                const float* Af = (const float*)Ap;
                const float4* rowp = (const float4*)(Af + (size_t)(row0 + r) * KDIM);
                float4 f0 = rowp[2 * c];
                float4 f1 = rowp[2 * c + 1];
                v.x = (u32)f2bf(f0.x) | ((u32)f2bf(f0.y) << 16);
                v.y = (u32)f2bf(f0.z) | ((u32)f2bf(f0.w) << 16);
                v.z = (u32)f2bf(f1.x) | ((u32)f2bf(f1.y) << 16);
                v.w = (u32)f2bf(f1.z) | ((u32)f2bf(f1.w) << 16);
            } else {
                const u16* Ab = (const u16*)Ap;
                v = ((const uint4*)(Ab + (size_t)(row0 + r) * KDIM))[c];
            }
        }
        ((uint4*)(As + r * KP))[c] = v;
    }
#pragma unroll
    for (int i = 0; i < 8; i++) {
        int idx = tid + i * 256;
        int r = idx >> 4, c = idx & 15;
        uint4 v = ((const uint4*)(Bt + (size_t)(col0 + r) * KDIM))[c];
        ((uint4*)(Bs + r * KP))[c] = v;
    }
    __syncthreads();

    const int lane = tid & 63, wave = tid >> 6;
    const int quad = lane >> 4, l16 = lane & 15;
    const int wcol = wave * 32;

    f32x4 acc[4][2];
#pragma unroll
    for (int mt = 0; mt < 4; mt++)
#pragma unroll
        for (int nt = 0; nt < 2; nt++) acc[mt][nt] = (f32x4){0.f, 0.f, 0.f, 0.f};

#pragma unroll
    for (int kc = 0; kc < 4; kc++) {
        short8 a[4], b[2];
#pragma unroll
        for (int mt = 0; mt < 4; mt++)
            a[mt] = *(const short8*)(As + (size_t)(mt * 16 + l16) * KP + kc * 32 + quad * 8);
#pragma unroll
        for (int nt = 0; nt < 2; nt++)
            b[nt] = *(const short8*)(Bs + (size_t)(wcol + nt * 16 + l16) * KP + kc * 32 + quad * 8);
#pragma unroll
        for (int mt = 0; mt < 4; mt++)
#pragma unroll
            for (int nt = 0; nt < 2; nt++)
                acc[mt][nt] = __builtin_amdgcn_mfma_f32_16x16x32_bf16(a[mt], b[nt], acc[mt][nt], 0, 0, 0);
    }

    // Epilogue: C/D layout col=lane&15, row=quad*4+reg [verified m89/m91].
    // Scalar 2B stores scatter badly -> round-trip through As (dead after MFMAs)
    // and store coalesced 16 B/lane.
    __syncthreads();                                    // all waves done reading As/Bs
#pragma unroll
    for (int mt = 0; mt < 4; mt++)
#pragma unroll
        for (int i = 0; i < 4; i++) {
            int rl = mt * 16 + quad * 4 + i;
#pragma unroll
            for (int nt = 0; nt < 2; nt++)
                As[rl * KP + wcol + nt * 16 + l16] = f2bf(acc[mt][nt][i]);
        }
    __syncthreads();
#pragma unroll
    for (int it = 0; it < 4; it++) {
        int idx = tid + it * 256;
        int r = idx >> 4, c8 = idx & 15;                // 16 x uint4 per 128-col row
        if (row0 + r < M)
            *(uint4*)(C + (size_t)(row0 + r) * NCOLS + col0 + c8 * 8) =
                *(const uint4*)(As + r * KP + c8 * 8);
    }
}

// ---------------- 128-col aggregation: 1 node/wave, 4 slots x 16 lanes, 4 gathers in flight ----------------
// out2 = [M+1][256] bf16 (s | t); row M is a zero row (OOB pad target).
template <bool RELU>
__global__ __launch_bounds__(256) void agg128_k(const u16* __restrict__ out2,
                                                const int* __restrict__ rowptr,
                                                const int* __restrict__ cols,
                                                const float* __restrict__ invd,
                                                const float* __restrict__ bias,
                                                u16* __restrict__ outp, int Mn) {
    int wave = threadIdx.x >> 6, lane = threadIdx.x & 63;
    int node = blockIdx.x * 4 + wave;
    if (node >= Mn) return;
    int sub = lane >> 4, l16 = lane & 15;               // 4 slots x 16 lanes
    const u16* tb = out2 + 128 + 8 * l16;
    int beg = rowptr[node], end = rowptr[node + 1];
    float2 a[4];
#pragma unroll
    for (int i = 0; i < 4; i++) a[i] = make_float2(0.f, 0.f);
    int e = beg + sub;
    while (e < end) {
        // cols is padded by 32 ints, so speculative loads are in-bounds;
        // OOB slots redirect to the zero row (index Mn) -> no register zeroing.
        int s0 = cols[e];                               // e < end guaranteed by loop cond
        int s1 = (e + 4  < end) ? cols[e + 4]  : Mn;
        int s2 = (e + 8  < end) ? cols[e + 8]  : Mn;
        int s3 = (e + 12 < end) ? cols[e + 12] : Mn;
        uint4 v0 = *(const uint4*)(tb + (size_t)s0 * 256);
        uint4 v1 = *(const uint4*)(tb + (size_t)s1 * 256);
        uint4 v2 = *(const uint4*)(tb + (size_t)s2 * 256);
        uint4 v3 = *(const uint4*)(tb + (size_t)s3 * 256);
        acc_u4p(a, v0); acc_u4p(a, v1); acc_u4p(a, v2); acc_u4p(a, v3);
        e += 16;
    }
    float af[8] = {a[0].x, a[0].y, a[1].x, a[1].y, a[2].x, a[2].y, a[3].x, a[3].y};
#pragma unroll
    for (int j = 0; j < 8; j++) {                       // reduce across 4 slots
        af[j] += __shfl_xor(af[j], 16); af[j] += __shfl_xor(af[j], 32);
    }
    if (sub == 0) {
        float id = invd[node];
        uint4 sv = *(const uint4*)(out2 + (size_t)node * 256 + 8 * l16);
        float4 b0 = *(const float4*)(bias + 8 * l16);
        float4 b1 = *(const float4*)(bias + 8 * l16 + 4);
        float o0 = bf2f(sv.x & 0xffffu) + af[0] * id + b0.x;
        float o1 = bf2f(sv.x >> 16)     + af[1] * id + b0.y;
        float o2 = bf2f(sv.y & 0xffffu) + af[2] * id + b0.z;
        float o3 = bf2f(sv.y >> 16)     + af[3] * id + b0.w;
        float o4 = bf2f(sv.z & 0xffffu) + af[4] * id + b1.x;
        float o5 = bf2f(sv.z >> 16)     + af[5] * id + b1.y;
        float o6 = bf2f(sv.w & 0xffffu) + af[6] * id + b1.z;
        float o7 = bf2f(sv.w >> 16)     + af[7] * id + b1.w;
        if (RELU) {
            o0 = fmaxf(o0, 0.f); o1 = fmaxf(o1, 0.f); o2 = fmaxf(o2, 0.f); o3 = fmaxf(o3, 0.f);
            o4 = fmaxf(o4, 0.f); o5 = fmaxf(o5, 0.f); o6 = fmaxf(o6, 0.f); o7 = fmaxf(o7, 0.f);
        }
        uint4 w;
        w.x = (u32)f2bf(o0) | ((u32)f2bf(o1) << 16);
        w.y = (u32)f2bf(o2) | ((u32)f2bf(o3) << 16);
        w.z = (u32)f2bf(o4) | ((u32)f2bf(o5) << 16);
        w.w = (u32)f2bf(o6) | ((u32)f2bf(o7) << 16);
        *(uint4*)(outp + (size_t)node * 128 + 8 * l16) = w;
    }
}

// ---------------- layer-2 aggregation: 1 node/wave, 8 slots x 8 lanes, 4 gathers in flight ----------------
// out2 = [M+1][128] bf16: s at cols 0..63 (live 0..46), t at cols 64..127 (live 64..110).
// Row M is a zero row (memset just before this kernel).
__global__ __launch_bounds__(256) void agg_out8_k(const u16* __restrict__ out2,
                                                  const int* __restrict__ rowptr,
                                                  const int* __restrict__ cols,
                                                  const float* __restrict__ invd,
                                                  const float* __restrict__ bias,
                                                  float* __restrict__ outp, int Mn) {
    int wave = threadIdx.x >> 6, lane = threadIdx.x & 63;
    int node = blockIdx.x * 4 + wave;
    if (node >= Mn) return;
    int e8 = lane >> 3, l8 = lane & 7;                  // 8 slots x 8 lanes
    const u16* tb = out2 + 64 + 8 * l8;
    int beg = rowptr[node], end = rowptr[node + 1];
    float2 a[4];
#pragma unroll
    for (int i = 0; i < 4; i++) a[i] = make_float2(0.f, 0.f);
    int e = beg + e8;
    while (e < end) {
        int s0 = cols[e];
        int s1 = (e + 8  < end) ? cols[e + 8]  : Mn;
        int s2 = (e + 16 < end) ? cols[e + 16] : Mn;
        int s3 = (e + 24 < end) ? cols[e + 24] : Mn;
        uint4 v0 = *(const uint4*)(tb + (size_t)s0 * 128);
        uint4 v1 = *(const uint4*)(tb + (size_t)s1 * 128);
        uint4 v2 = *(const uint4*)(tb + (size_t)s2 * 128);
        uint4 v3 = *(const uint4*)(tb + (size_t)s3 * 128);
        acc_u4p(a, v0); acc_u4p(a, v1); acc_u4p(a, v2); acc_u4p(a, v3);
        e += 32;
    }
    float af[8] = {a[0].x, a[0].y, a[1].x, a[1].y, a[2].x, a[2].y, a[3].x, a[3].y};
#pragma unroll
    for (int j = 0; j < 8; j++) {                       // reduce across 8 slots
        af[j] += __shfl_xor(af[j], 8); af[j] += __shfl_xor(af[j], 16); af[j] += __shfl_xor(af[j], 32);
    }
    if (e8 == 0) {
        float id = invd[node];
        uint4 sv = *(const uint4*)(out2 + (size_t)node * 128 + 8 * l8);
        u32 sw[4] = {sv.x, sv.y, sv.z, sv.w};
        float* orow = outp + (size_t)node * 47;
#pragma unroll
        for (int j = 0; j < 8; j++) {
            int c = 8 * l8 + j;
            if (c < 47) {
                float s = bf2f((j & 1) ? (sw[j >> 1] >> 16) : (sw[j >> 1] & 0xffffu));
                orow[c] = s + af[j] * id + bias[c];
            }
        }
    }
}

// ---------------- launch ----------------

extern "C" void kernel_launch(void* const* d_in, const int* in_sizes, int n_in,
                              void* d_out, int out_size, void* d_ws, size_t ws_size,
                              hipStream_t stream) {
    const float* x   = (const float*)d_in[0];
    const int*   src = (const int*)d_in[1];
    const int*   dst = (const int*)d_in[2];
    const float* ws0 = (const float*)d_in[3];
    const float* wn0 = (const float*)d_in[4];
    const float* b0  = (const float*)d_in[5];
    const float* ws1 = (const float*)d_in[6];
    const float* wn1 = (const float*)d_in[7];
    const float* b1  = (const float*)d_in[8];
    const float* ws2 = (const float*)d_in[9];
    const float* wn2 = (const float*)d_in[10];
    const float* b2  = (const float*)d_in[11];

    const int Nn = in_sizes[0] / 128;   // 100000
    const int E  = in_sizes[1];         // 1600000

    char* p = (char*)d_ws;
    auto alloc = [&](size_t bytes) -> void* {
        void* r = (void*)p;
        p += (bytes + 255) & ~(size_t)255;
        return r;
    };
    u16*   bufA   = (u16*)alloc((size_t)Nn * 128 * 2);            // h1 / h2
    u16*   out2   = (u16*)alloc(((size_t)Nn * 256 + 256) * 2);    // [s|t] per layer + 1 zero pad row; ALSO overlaid as pairs buf
    u16*   wt0    = (u16*)alloc(256 * 128 * 2);
    u16*   wt1    = (u16*)alloc(256 * 128 * 2);
    u16*   wt2    = (u16*)alloc(128 * 128 * 2);
    int*   rowptr = (int*)alloc((size_t)(Nn + 1) * 4);
    float* invd   = (float*)alloc((size_t)Nn * 4);
    int*   cols   = (int*)alloc((size_t)(E + 32) * 4);            // +32 pad: speculative in-flight loads
    int*   bcnt   = (int*)alloc(256 * 4);
    int*   boff   = (int*)alloc(257 * 4);
    int*   cursor = (int*)alloc(256 * 4);
    uint2* pairs  = (uint2*)out2;                                 // overlay: out2 unused until gemm layer 0

    hipMemsetAsync(bcnt, 0, 256 * 4, stream);
    // zero pad row for the 256-col layout (row Nn, byte offset Nn*512; beyond pairs overlay)
    hipMemsetAsync(out2 + (size_t)Nn * 256, 0, 512, stream);

    prep_w_all<<<320, 256, 0, stream>>>(ws0, wn0, wt0, ws1, wn1, wt1, ws2, wn2, wt2);

    hist256<<<512, 256, 0, stream>>>(dst, bcnt, E);
    scan256<<<1, 256, 0, stream>>>(bcnt, boff, cursor);

    bucket_scatter<<<(E + TILE - 1) / TILE, 512, 0, stream>>>(src, dst, cursor, pairs, E);
    build_csr2<<<(Nn + 511) / 512, 512, 0, stream>>>(pairs, boff, rowptr, invd, cols, Nn, E);

    dim3 ggrid((Nn + 63) / 64, 2);
    dim3 ggrid1((Nn + 63) / 64, 1);
    const int aggGrid = (Nn + 3) / 4;                    // 4 waves x 1 node = 4 nodes/block
    // layer 0: LDS-staged GEMM reads x fp32 directly (cvt fused into staging)
    gemm_bf16<256, true><<<ggrid, 256, 0, stream>>>(x, wt0, out2, Nn);
    agg128_k<true><<<aggGrid, 256, 0, stream>>>(out2, rowptr, cols, invd, b0, bufA, Nn);
    // layer 1
    gemm_bf16<256, false><<<ggrid, 256, 0, stream>>>(bufA, wt1, out2, Nn);
    agg128_k<true><<<aggGrid, 256, 0, stream>>>(out2, rowptr, cols, invd, b1, bufA, Nn);
    // layer 2: N=128 (48 self + 48 neigh, padded)
    gemm_bf16<128, false><<<ggrid1, 256, 0, stream>>>(bufA, wt2, out2, Nn);
    // zero pad row for the 128-col layout (row Nn, byte offset Nn*256); must be after
    // layer-1 consumers of that region (stream-ordered here, after gemm<128>)
    hipMemsetAsync(out2 + (size_t)Nn * 128, 0, 256, stream);
    agg_out8_k<<<aggGrid, 256, 0, stream>>>(out2, rowptr, cols, invd, b2, (float*)d_out, Nn);
}